// Round 1
// baseline (290.057 us; speedup 1.0000x reference)
//
#include <hip/hip_runtime.h>
#include <hip/hip_bf16.h>
#include <math.h>

#define BIGF 1e8f
// gamma = 0.1, warp = 1.0
// softmin_g(a,b,c) = m - g*ln2 * log2( 2^{(m-a)/(g ln2)} + ... ), m = min3
#define C1 14.4269504088896f   // 1/(gamma*ln2)
#define C2 0.069314718055995f  // gamma*ln2

__device__ inline float fast_exp2(float x) {
#if __has_builtin(__builtin_amdgcn_exp2f)
    return __builtin_amdgcn_exp2f(x);
#else
    return exp2f(x);
#endif
}
__device__ inline float fast_log2(float x) {
#if __has_builtin(__builtin_amdgcn_logf)
    return __builtin_amdgcn_logf(x);
#else
    return log2f(x);
#endif
}

// ---------------------------------------------------------------------------
// Kernel A: cost matrix in diagonal-major layout.
// Ddiag[b][k][i] = sum_d |pred[b,i,d] - targ[b,k-i,d]|  (k = i+j)
// grid (8,8,4): 64x64 output tile per block, 256 threads, 4x4 per thread.
// ---------------------------------------------------------------------------
__global__ __launch_bounds__(256) void cost_kernel(
        const float* __restrict__ pred, const float* __restrict__ targ,
        float* __restrict__ Ddiag) {
    const int b  = blockIdx.z;
    const int i0 = blockIdx.y * 64;
    const int j0 = blockIdx.x * 64;
    __shared__ float sp[64][81];
    __shared__ float st[64][81];
    const int t = threadIdx.x;

    const float4* __restrict__ p4 = (const float4*)(pred + ((size_t)b * 512 + i0) * 80);
    const float4* __restrict__ t4 = (const float4*)(targ + ((size_t)b * 512 + j0) * 80);
    // 64 rows x 20 float4 = 1280 float4 per matrix; 256 threads -> 5 each
    #pragma unroll
    for (int q = 0; q < 5; ++q) {
        int idx = q * 256 + t;       // 0..1279
        int r = idx / 20, dq = idx % 20;
        float4 v = p4[r * 20 + dq];
        sp[r][dq*4+0] = v.x; sp[r][dq*4+1] = v.y; sp[r][dq*4+2] = v.z; sp[r][dq*4+3] = v.w;
        float4 w = t4[r * 20 + dq];
        st[r][dq*4+0] = w.x; st[r][dq*4+1] = w.y; st[r][dq*4+2] = w.z; st[r][dq*4+3] = w.w;
    }
    __syncthreads();

    const int tx = t & 15, ty = t >> 4;
    float acc[4][4];
    #pragma unroll
    for (int r = 0; r < 4; ++r)
        #pragma unroll
        for (int c = 0; c < 4; ++c) acc[r][c] = 0.f;

    #pragma unroll 4
    for (int d = 0; d < 80; ++d) {
        float a0 = sp[4*ty+0][d], a1 = sp[4*ty+1][d], a2 = sp[4*ty+2][d], a3 = sp[4*ty+3][d];
        float b0 = st[4*tx+0][d], b1 = st[4*tx+1][d], b2 = st[4*tx+2][d], b3 = st[4*tx+3][d];
        acc[0][0] += fabsf(a0-b0); acc[0][1] += fabsf(a0-b1); acc[0][2] += fabsf(a0-b2); acc[0][3] += fabsf(a0-b3);
        acc[1][0] += fabsf(a1-b0); acc[1][1] += fabsf(a1-b1); acc[1][2] += fabsf(a1-b2); acc[1][3] += fabsf(a1-b3);
        acc[2][0] += fabsf(a2-b0); acc[2][1] += fabsf(a2-b1); acc[2][2] += fabsf(a2-b2); acc[2][3] += fabsf(a2-b3);
        acc[3][0] += fabsf(a3-b0); acc[3][1] += fabsf(a3-b1); acc[3][2] += fabsf(a3-b2); acc[3][3] += fabsf(a3-b3);
    }

    #pragma unroll
    for (int r = 0; r < 4; ++r) {
        #pragma unroll
        for (int c = 0; c < 4; ++c) {
            int i = i0 + 4*ty + r;
            int j = j0 + 4*tx + c;
            Ddiag[((size_t)b * 1023 + (i + j)) * 512 + i] = acc[r][c];
        }
    }
}

// ---------------------------------------------------------------------------
// Kernel B: soft-DTW wavefront DP. One block per batch, 512 threads = 8 waves.
// Thread i owns row i; V1 = V_{k-1}[i], V2 = V_{k-2}[i].
// Cell (i, j=k-i):  V_k[i] = D[i][j] + softmin(V2[i-1], V1[i-1]+w, V1[i]+w)
// Cross-wave boundary via double-buffered LDS (one barrier per step).
// ---------------------------------------------------------------------------
__global__ __launch_bounds__(512) void dp_kernel(
        const float* __restrict__ Ddiag, float* __restrict__ sdtw) {
    const int b    = blockIdx.x;
    const int i    = threadIdx.x;     // row 0..511
    const int wave = i >> 6;
    const int lane = i & 63;

    __shared__ float S1[2][8];
    __shared__ float S2[2][8];
    if (i < 8) { S1[0][i] = BIGF; S1[1][i] = BIGF; S2[0][i] = BIGF; S2[1][i] = BIGF; }
    __syncthreads();

    float V1 = BIGF, V2 = BIGF;
    const float* __restrict__ Db = Ddiag + (size_t)b * 1023 * 512;
    float dcur = Db[i];               // D for step k=0

    for (int k = 0; k < 1023; ++k) {
        // prefetch next diagonal's cost (coalesced)
        float dnext = 0.f;
        if (k + 1 < 1023) dnext = Db[(size_t)(k + 1) * 512 + i];

        const int src = k & 1, dst = src ^ 1;

        float nb1 = __shfl_up(V1, 1);
        float nb2 = __shfl_up(V2, 1);
        // cross-wave boundary (broadcast LDS read, then select for lane 0)
        float ls1 = S1[src][(wave + 7) & 7];
        float ls2 = S2[src][(wave + 7) & 7];
        if (lane == 0) {
            nb1 = (wave > 0) ? ls1 : BIGF;
            nb2 = (wave > 0) ? ls2 : BIGF;
        }

        const int j = k - i;
        const bool valid = (j >= 0) && (j < 512);

        float rd = (i == 0) ? ((j == 0) ? 0.f : BIGF) : ((j == 0) ? BIGF : nb2);
        float ru = (i == 0) ? BIGF : nb1 + 1.0f;   // warp = 1.0
        float rl = (j == 0) ? BIGF : V1 + 1.0f;

        float m = fminf(fminf(rd, ru), rl);
        float s = fast_exp2(C1 * (m - rd)) + fast_exp2(C1 * (m - ru)) + fast_exp2(C1 * (m - rl));
        float smin = m - C2 * fast_log2(s);
        float Vn = valid ? (dcur + smin) : BIGF;

        if (lane == 63) { S1[dst][wave] = Vn; S2[dst][wave] = V1; }
        __syncthreads();

        V2 = V1; V1 = Vn; dcur = dnext;
    }
    if (i == 511) sdtw[b] = V1;       // R[N, M]
}

// ---------------------------------------------------------------------------
// Kernel C: duration loss + final scalar.
// out = mean_b(sdtw[b]/512) + mean(|log_d_pred - log(d_target+1)|)
// ---------------------------------------------------------------------------
__global__ __launch_bounds__(512) void finalize_kernel(
        const float* __restrict__ ldp, const int* __restrict__ dt,
        const float* __restrict__ sdtw, float* __restrict__ out) {
    const int t = threadIdx.x;        // 512 threads, 512 duration elems
    float v = fabsf(ldp[t] - logf((float)dt[t] + 1.0f));
    #pragma unroll
    for (int o = 32; o > 0; o >>= 1) v += __shfl_down(v, o);
    __shared__ float part[8];
    if ((t & 63) == 0) part[t >> 6] = v;
    __syncthreads();
    if (t == 0) {
        float dur = 0.f;
        #pragma unroll
        for (int w = 0; w < 8; ++w) dur += part[w];
        dur *= (1.0f / 512.0f);
        float mel = (sdtw[0] + sdtw[1] + sdtw[2] + sdtw[3]) * (1.0f / (4.0f * 512.0f));
        out[0] = mel + dur;
    }
}

extern "C" void kernel_launch(void* const* d_in, const int* in_sizes, int n_in,
                              void* d_out, int out_size, void* d_ws, size_t ws_size,
                              hipStream_t stream) {
    const float* pred = (const float*)d_in[0];   // mel_pred  [4,512,80]
    const float* targ = (const float*)d_in[1];   // mel_target[4,512,80]
    const float* ldp  = (const float*)d_in[2];   // log_d_pred[4,128]
    const int*   dt   = (const int*)d_in[3];     // d_target  [4,128]
    float* out = (float*)d_out;

    float* Ddiag = (float*)d_ws;                          // 4*1023*512 floats = 8.38 MB
    float* sdtw  = Ddiag + (size_t)4 * 1023 * 512;        // 4 floats

    cost_kernel<<<dim3(8, 8, 4), 256, 0, stream>>>(pred, targ, Ddiag);
    dp_kernel<<<4, 512, 0, stream>>>(Ddiag, sdtw);
    finalize_kernel<<<1, 512, 0, stream>>>(ldp, dt, sdtw, out);
}

// Round 2
// 159.333 us; speedup vs baseline: 1.8204x; 1.8204x over previous
//
#include <hip/hip_runtime.h>
#include <hip/hip_bf16.h>
#include <math.h>

#define BIGF 1e8f

// ---------------------------------------------------------------------------
// Fill Ddiag with BIG so invalid (i,j) slots propagate huge values in the DP
// (removes all per-cell boundary checks from the hot loop).
// ---------------------------------------------------------------------------
__global__ __launch_bounds__(256) void fill_kernel(float* __restrict__ p, int n4) {
    int idx = blockIdx.x * 256 + threadIdx.x;
    if (idx < n4) ((float4*)p)[idx] = make_float4(BIGF, BIGF, BIGF, BIGF);
}

// ---------------------------------------------------------------------------
// Kernel A: cost matrix in diagonal-major layout.
// Ddiag[b][k][i] = sum_d |pred[b,i,d] - targ[b,k-i,d]|  (k = i+j)
// ---------------------------------------------------------------------------
__global__ __launch_bounds__(256) void cost_kernel(
        const float* __restrict__ pred, const float* __restrict__ targ,
        float* __restrict__ Ddiag) {
    const int b  = blockIdx.z;
    const int i0 = blockIdx.y * 64;
    const int j0 = blockIdx.x * 64;
    __shared__ float sp[64][81];
    __shared__ float st[64][81];
    const int t = threadIdx.x;

    const float4* __restrict__ p4 = (const float4*)(pred + ((size_t)b * 512 + i0) * 80);
    const float4* __restrict__ t4 = (const float4*)(targ + ((size_t)b * 512 + j0) * 80);
    #pragma unroll
    for (int q = 0; q < 5; ++q) {
        int idx = q * 256 + t;       // 0..1279
        int r = idx / 20, dq = idx % 20;
        float4 v = p4[r * 20 + dq];
        sp[r][dq*4+0] = v.x; sp[r][dq*4+1] = v.y; sp[r][dq*4+2] = v.z; sp[r][dq*4+3] = v.w;
        float4 w = t4[r * 20 + dq];
        st[r][dq*4+0] = w.x; st[r][dq*4+1] = w.y; st[r][dq*4+2] = w.z; st[r][dq*4+3] = w.w;
    }
    __syncthreads();

    const int tx = t & 15, ty = t >> 4;
    float acc[4][4];
    #pragma unroll
    for (int r = 0; r < 4; ++r)
        #pragma unroll
        for (int c = 0; c < 4; ++c) acc[r][c] = 0.f;

    #pragma unroll 4
    for (int d = 0; d < 80; ++d) {
        float a0 = sp[4*ty+0][d], a1 = sp[4*ty+1][d], a2 = sp[4*ty+2][d], a3 = sp[4*ty+3][d];
        float b0 = st[4*tx+0][d], b1 = st[4*tx+1][d], b2 = st[4*tx+2][d], b3 = st[4*tx+3][d];
        acc[0][0] += fabsf(a0-b0); acc[0][1] += fabsf(a0-b1); acc[0][2] += fabsf(a0-b2); acc[0][3] += fabsf(a0-b3);
        acc[1][0] += fabsf(a1-b0); acc[1][1] += fabsf(a1-b1); acc[1][2] += fabsf(a1-b2); acc[1][3] += fabsf(a1-b3);
        acc[2][0] += fabsf(a2-b0); acc[2][1] += fabsf(a2-b1); acc[2][2] += fabsf(a2-b2); acc[2][3] += fabsf(a2-b3);
        acc[3][0] += fabsf(a3-b0); acc[3][1] += fabsf(a3-b1); acc[3][2] += fabsf(a3-b2); acc[3][3] += fabsf(a3-b3);
    }

    #pragma unroll
    for (int r = 0; r < 4; ++r) {
        #pragma unroll
        for (int c = 0; c < 4; ++c) {
            int i = i0 + 4*ty + r;
            int j = j0 + 4*tx + c;
            Ddiag[((size_t)b * 1023 + (i + j)) * 512 + i] = acc[r][c];
        }
    }
}

// ---------------------------------------------------------------------------
// Kernel B: soft-DTW wavefront DP, min3 approximation (bias <= gamma*ln3 per
// cell, worst-case 0.22 on the final scalar vs 1.84 tolerance).
// ONE WAVE per batch, lane owns rows 8*lane..8*lane+7. No LDS, no barriers.
// Ping-pong register arrays A/B; D prefetched 8 diagonals ahead.
// ---------------------------------------------------------------------------
#define STEP(V1, V2, da, db, kk)                                             \
  {                                                                          \
    float nb1 = __shfl_up(V1[7], 1);                                         \
    float nb2 = __shfl_up(V2[7], 1);                                         \
    if (lane == 0) { nb1 = BIGF; nb2 = ((kk) == 0) ? 0.0f : BIGF; }          \
    V2[7] = db.w + fminf(fminf(V2[6], V1[6] + 1.0f), V1[7] + 1.0f);          \
    V2[6] = db.z + fminf(fminf(V2[5], V1[5] + 1.0f), V1[6] + 1.0f);          \
    V2[5] = db.y + fminf(fminf(V2[4], V1[4] + 1.0f), V1[5] + 1.0f);          \
    V2[4] = db.x + fminf(fminf(V2[3], V1[3] + 1.0f), V1[4] + 1.0f);          \
    V2[3] = da.w + fminf(fminf(V2[2], V1[2] + 1.0f), V1[3] + 1.0f);          \
    V2[2] = da.z + fminf(fminf(V2[1], V1[1] + 1.0f), V1[2] + 1.0f);          \
    V2[1] = da.y + fminf(fminf(V2[0], V1[0] + 1.0f), V1[1] + 1.0f);          \
    V2[0] = da.x + fminf(fminf(nb2,   nb1  + 1.0f), V1[0] + 1.0f);           \
  }

__global__ __launch_bounds__(64) void dp_kernel(
        const float* __restrict__ Ddiag, float* __restrict__ sdtw) {
    const int b    = blockIdx.x;
    const int lane = threadIdx.x;
    const float* __restrict__ Db = Ddiag + (size_t)b * 1023 * 512 + (lane << 3);

    float A[8], B[8];
    #pragma unroll
    for (int r = 0; r < 8; ++r) { A[r] = BIGF; B[r] = BIGF; }

    float4 Pa[8], Pb[8];
    #pragma unroll
    for (int p = 0; p < 8; ++p) {
        Pa[p] = *(const float4*)(Db + (size_t)p * 512);
        Pb[p] = *(const float4*)(Db + (size_t)p * 512 + 4);
    }

    int k0 = 0;
    for (int t = 0; t < 127; ++t, k0 += 8) {
#define PH(p, Vx, Vy)                                                        \
        STEP(Vx, Vy, Pa[p], Pb[p], k0 + p)                                   \
        {                                                                    \
            int kp = k0 + 8 + (p); if (kp > 1022) kp = 1022;                 \
            const float* src = Db + (size_t)kp * 512;                        \
            Pa[p] = *(const float4*)(src);                                   \
            Pb[p] = *(const float4*)(src + 4);                               \
        }
        PH(0, A, B) PH(1, B, A) PH(2, A, B) PH(3, B, A)
        PH(4, A, B) PH(5, B, A) PH(6, A, B) PH(7, B, A)
#undef PH
    }
    // tail: k = 1016..1022 (7 steps)
    STEP(A, B, Pa[0], Pb[0], 1016)
    STEP(B, A, Pa[1], Pb[1], 1017)
    STEP(A, B, Pa[2], Pb[2], 1018)
    STEP(B, A, Pa[3], Pb[3], 1019)
    STEP(A, B, Pa[4], Pb[4], 1020)
    STEP(B, A, Pa[5], Pb[5], 1021)
    STEP(A, B, Pa[6], Pb[6], 1022)

    if (lane == 63) sdtw[b] = B[7];   // R[512,512] == cell (511,511)
}

// ---------------------------------------------------------------------------
// Kernel C: duration loss + final scalar.
// ---------------------------------------------------------------------------
__global__ __launch_bounds__(512) void finalize_kernel(
        const float* __restrict__ ldp, const int* __restrict__ dt,
        const float* __restrict__ sdtw, float* __restrict__ out) {
    const int t = threadIdx.x;        // 512 threads, 512 duration elems
    float v = fabsf(ldp[t] - logf((float)dt[t] + 1.0f));
    #pragma unroll
    for (int o = 32; o > 0; o >>= 1) v += __shfl_down(v, o);
    __shared__ float part[8];
    if ((t & 63) == 0) part[t >> 6] = v;
    __syncthreads();
    if (t == 0) {
        float dur = 0.f;
        #pragma unroll
        for (int w = 0; w < 8; ++w) dur += part[w];
        dur *= (1.0f / 512.0f);
        float mel = (sdtw[0] + sdtw[1] + sdtw[2] + sdtw[3]) * (1.0f / (4.0f * 512.0f));
        out[0] = mel + dur;
    }
}

extern "C" void kernel_launch(void* const* d_in, const int* in_sizes, int n_in,
                              void* d_out, int out_size, void* d_ws, size_t ws_size,
                              hipStream_t stream) {
    const float* pred = (const float*)d_in[0];   // mel_pred  [4,512,80]
    const float* targ = (const float*)d_in[1];   // mel_target[4,512,80]
    const float* ldp  = (const float*)d_in[2];   // log_d_pred[4,128]
    const int*   dt   = (const int*)d_in[3];     // d_target  [4,128]
    float* out = (float*)d_out;

    float* Ddiag = (float*)d_ws;                          // 4*1023*512 floats = 8.38 MB
    float* sdtw  = Ddiag + (size_t)4 * 1023 * 512;        // 4 floats

    fill_kernel<<<2046, 256, 0, stream>>>(Ddiag, 523776);
    cost_kernel<<<dim3(8, 8, 4), 256, 0, stream>>>(pred, targ, Ddiag);
    dp_kernel<<<4, 64, 0, stream>>>(Ddiag, sdtw);
    finalize_kernel<<<1, 512, 0, stream>>>(ldp, dt, sdtw, out);
}

// Round 3
// 112.643 us; speedup vs baseline: 2.5750x; 1.4145x over previous
//
#include <hip/hip_runtime.h>
#include <hip/hip_bf16.h>
#include <math.h>

#define BIGF 1e8f

// ---------------------------------------------------------------------------
// prep_kernel: blocks 0..255 compute the cost matrix (diagonal-major layout);
// blocks 256..1278 fill the INVALID slots with BIG. Writes are disjoint.
// Ddiag[b][k][i] = sum_d |pred[b,i,d] - targ[b,k-i,d]|   (k = i+j)
// Slot (b,0,0) stores D(0,0) - 1e8 so the DP start condition needs no branch.
// ---------------------------------------------------------------------------
__global__ __launch_bounds__(256) void prep_kernel(
        const float* __restrict__ pred, const float* __restrict__ targ,
        float* __restrict__ Ddiag) {
    const int bid = blockIdx.x;
    const int t   = threadIdx.x;

    if (bid < 256) {
        const int b  = bid >> 6;
        const int i0 = ((bid >> 3) & 7) * 64;
        const int j0 = (bid & 7) * 64;
        __shared__ float sp[64][81];
        __shared__ float st[64][81];

        const float4* __restrict__ p4 = (const float4*)(pred + ((size_t)b * 512 + i0) * 80);
        const float4* __restrict__ t4 = (const float4*)(targ + ((size_t)b * 512 + j0) * 80);
        #pragma unroll
        for (int q = 0; q < 5; ++q) {
            int idx = q * 256 + t;       // 0..1279
            int r = idx / 20, dq = idx % 20;
            float4 v = p4[r * 20 + dq];
            sp[r][dq*4+0]=v.x; sp[r][dq*4+1]=v.y; sp[r][dq*4+2]=v.z; sp[r][dq*4+3]=v.w;
            float4 w = t4[r * 20 + dq];
            st[r][dq*4+0]=w.x; st[r][dq*4+1]=w.y; st[r][dq*4+2]=w.z; st[r][dq*4+3]=w.w;
        }
        __syncthreads();

        const int tx = t & 15, ty = t >> 4;
        float acc[4][4];
        #pragma unroll
        for (int r = 0; r < 4; ++r)
            #pragma unroll
            for (int c = 0; c < 4; ++c) acc[r][c] = 0.f;

        #pragma unroll 4
        for (int d = 0; d < 80; ++d) {
            float a0 = sp[4*ty+0][d], a1 = sp[4*ty+1][d], a2 = sp[4*ty+2][d], a3 = sp[4*ty+3][d];
            float b0 = st[4*tx+0][d], b1 = st[4*tx+1][d], b2 = st[4*tx+2][d], b3 = st[4*tx+3][d];
            acc[0][0] += fabsf(a0-b0); acc[0][1] += fabsf(a0-b1); acc[0][2] += fabsf(a0-b2); acc[0][3] += fabsf(a0-b3);
            acc[1][0] += fabsf(a1-b0); acc[1][1] += fabsf(a1-b1); acc[1][2] += fabsf(a1-b2); acc[1][3] += fabsf(a1-b3);
            acc[2][0] += fabsf(a2-b0); acc[2][1] += fabsf(a2-b1); acc[2][2] += fabsf(a2-b2); acc[2][3] += fabsf(a2-b3);
            acc[3][0] += fabsf(a3-b0); acc[3][1] += fabsf(a3-b1); acc[3][2] += fabsf(a3-b2); acc[3][3] += fabsf(a3-b3);
        }

        #pragma unroll
        for (int r = 0; r < 4; ++r) {
            #pragma unroll
            for (int c = 0; c < 4; ++c) {
                int i = i0 + 4*ty + r;
                int j = j0 + 4*tx + c;
                float v = acc[r][c];
                if ((i | j) == 0) v -= BIGF;   // start-condition trick
                Ddiag[((size_t)b * 1023 + (i + j)) * 512 + i] = v;
            }
        }
    } else {
        // fill invalid slots: slot space [0, 4*1023*512) scanned, write where j out of range
        unsigned fid  = bid - 256;                 // 0..1022
        unsigned base = fid * 2048u + (unsigned)t * 8u;
        #pragma unroll
        for (int e = 0; e < 8; ++e) {
            unsigned slot = base + e;              // < 2,095,104
            unsigned rem  = slot % 523776u;        // 1023*512
            int k = (int)(rem >> 9);
            int i = (int)(rem & 511u);
            int j = k - i;
            if ((unsigned)j >= 512u) Ddiag[slot] = BIGF;
        }
    }
}

// ---------------------------------------------------------------------------
// dp_kernel: soft-DTW wavefront DP (min3 approx). ONE wave per batch, lane
// owns rows 8*lane..8*lane+7. Cross-lane via v_mov_b32_dpp wave_shr:1
// (update_dpp: lane 0 keeps the BIGF 'old' value -> boundary handled free).
// 16-deep prefetch of the diagonal-major cost matrix.
// ---------------------------------------------------------------------------
#define STEP(V1, V2, da, db)                                                  \
  {                                                                           \
    float nb1 = __int_as_float(__builtin_amdgcn_update_dpp(                   \
        __float_as_int(BIGF), __float_as_int(V1[7]), 0x138, 0xF, 0xF, false));\
    float nb2 = __int_as_float(__builtin_amdgcn_update_dpp(                   \
        __float_as_int(BIGF), __float_as_int(V2[7]), 0x138, 0xF, 0xF, false));\
    V2[7] = db.w + fminf(V2[6], fminf(V1[6], V1[7]) + 1.0f);                  \
    V2[6] = db.z + fminf(V2[5], fminf(V1[5], V1[6]) + 1.0f);                  \
    V2[5] = db.y + fminf(V2[4], fminf(V1[4], V1[5]) + 1.0f);                  \
    V2[4] = db.x + fminf(V2[3], fminf(V1[3], V1[4]) + 1.0f);                  \
    V2[3] = da.w + fminf(V2[2], fminf(V1[2], V1[3]) + 1.0f);                  \
    V2[2] = da.z + fminf(V2[1], fminf(V1[1], V1[2]) + 1.0f);                  \
    V2[1] = da.y + fminf(V2[0], fminf(V1[0], V1[1]) + 1.0f);                  \
    V2[0] = da.x + fminf(nb2,   fminf(nb1,   V1[0]) + 1.0f);                  \
  }

__global__ __launch_bounds__(64) void dp_kernel(
        const float* __restrict__ Ddiag, float* __restrict__ sdtw) {
    const int b    = blockIdx.x;
    const int lane = threadIdx.x;
    const char* __restrict__ base = (const char*)Ddiag + (size_t)b * (1023ull * 512 * 4);
    const unsigned loff = (unsigned)lane * 32u;

    float A[8], B[8];
    #pragma unroll
    for (int r = 0; r < 8; ++r) { A[r] = BIGF; B[r] = BIGF; }

    float4 Pa[16], Pb[16];
    #pragma unroll
    for (int p = 0; p < 16; ++p) {
        const char* s = base + (size_t)p * 2048 + loff;
        Pa[p] = *(const float4*)(s);
        Pb[p] = *(const float4*)(s + 16);
    }

    int k0 = 0;
    for (int t = 0; t < 63; ++t, k0 += 16) {
#define PH(p, Vx, Vy)                                                         \
        STEP(Vx, Vy, Pa[p], Pb[p])                                            \
        {                                                                     \
            int kp = k0 + 16 + (p); kp = (kp > 1022) ? 1022 : kp;             \
            const char* s = base + (size_t)kp * 2048 + loff;                  \
            Pa[p] = *(const float4*)(s);                                      \
            Pb[p] = *(const float4*)(s + 16);                                 \
        }
        PH(0,A,B)  PH(1,B,A)  PH(2,A,B)  PH(3,B,A)
        PH(4,A,B)  PH(5,B,A)  PH(6,A,B)  PH(7,B,A)
        PH(8,A,B)  PH(9,B,A)  PH(10,A,B) PH(11,B,A)
        PH(12,A,B) PH(13,B,A) PH(14,A,B) PH(15,B,A)
#undef PH
    }
    // tail: k = 1008..1022 (15 steps), phases 0..14 already prefetched
    STEP(A,B,Pa[0],Pb[0])   STEP(B,A,Pa[1],Pb[1])   STEP(A,B,Pa[2],Pb[2])
    STEP(B,A,Pa[3],Pb[3])   STEP(A,B,Pa[4],Pb[4])   STEP(B,A,Pa[5],Pb[5])
    STEP(A,B,Pa[6],Pb[6])   STEP(B,A,Pa[7],Pb[7])   STEP(A,B,Pa[8],Pb[8])
    STEP(B,A,Pa[9],Pb[9])   STEP(A,B,Pa[10],Pb[10]) STEP(B,A,Pa[11],Pb[11])
    STEP(A,B,Pa[12],Pb[12]) STEP(B,A,Pa[13],Pb[13]) STEP(A,B,Pa[14],Pb[14])

    if (lane == 63) sdtw[b] = B[7];   // cell (511,511), k=1022 writes B
}

// ---------------------------------------------------------------------------
// finalize: duration loss + final scalar.
// ---------------------------------------------------------------------------
__global__ __launch_bounds__(512) void finalize_kernel(
        const float* __restrict__ ldp, const int* __restrict__ dt,
        const float* __restrict__ sdtw, float* __restrict__ out) {
    const int t = threadIdx.x;
    float v = fabsf(ldp[t] - logf((float)dt[t] + 1.0f));
    #pragma unroll
    for (int o = 32; o > 0; o >>= 1) v += __shfl_down(v, o);
    __shared__ float part[8];
    if ((t & 63) == 0) part[t >> 6] = v;
    __syncthreads();
    if (t == 0) {
        float dur = 0.f;
        #pragma unroll
        for (int w = 0; w < 8; ++w) dur += part[w];
        dur *= (1.0f / 512.0f);
        float mel = (sdtw[0] + sdtw[1] + sdtw[2] + sdtw[3]) * (1.0f / (4.0f * 512.0f));
        out[0] = mel + dur;
    }
}

extern "C" void kernel_launch(void* const* d_in, const int* in_sizes, int n_in,
                              void* d_out, int out_size, void* d_ws, size_t ws_size,
                              hipStream_t stream) {
    const float* pred = (const float*)d_in[0];   // mel_pred  [4,512,80]
    const float* targ = (const float*)d_in[1];   // mel_target[4,512,80]
    const float* ldp  = (const float*)d_in[2];   // log_d_pred[4,128]
    const int*   dt   = (const int*)d_in[3];     // d_target  [4,128]
    float* out = (float*)d_out;

    float* Ddiag = (float*)d_ws;                          // 4*1023*512 floats = 8.38 MB
    float* sdtw  = Ddiag + (size_t)4 * 1023 * 512;        // 4 floats

    prep_kernel<<<256 + 1023, 256, 0, stream>>>(pred, targ, Ddiag);
    dp_kernel<<<4, 64, 0, stream>>>(Ddiag, sdtw);
    finalize_kernel<<<1, 512, 0, stream>>>(ldp, dt, sdtw, out);
}

// Round 4
// 80.008 us; speedup vs baseline: 3.6254x; 1.4079x over previous
//
#include <hip/hip_runtime.h>
#include <hip/hip_bf16.h>
#include <math.h>

#define BIGF 1e8f

__device__ inline float min3f(float a, float b, float c) {
    float d;
    asm("v_min3_f32 %0, %1, %2, %3" : "=v"(d) : "v"(a), "v"(b), "v"(c));
    return d;
}

// ---------------------------------------------------------------------------
// prep_kernel: blocks 0..255 compute the cost matrix (diagonal-major layout);
// blocks 256..1278 fill the INVALID slots with BIG. Writes are disjoint.
// W-transform fold: every valid cell stores D+2 (W[k] = V[k]+k recurrence
// W[k] = (D+2) + min3(Wdiag, Wup, Wleft)); cell (0,0) stores D00 - 1e8 so the
// uniform first step produces W[0][0] = D00 with no branch in the DP.
// ---------------------------------------------------------------------------
__global__ __launch_bounds__(256) void prep_kernel(
        const float* __restrict__ pred, const float* __restrict__ targ,
        float* __restrict__ Ddiag) {
    const int bid = blockIdx.x;
    const int t   = threadIdx.x;

    if (bid < 256) {
        const int b  = bid >> 6;
        const int i0 = ((bid >> 3) & 7) * 64;
        const int j0 = (bid & 7) * 64;
        __shared__ float sp[64][81];
        __shared__ float st[64][81];

        const float4* __restrict__ p4 = (const float4*)(pred + ((size_t)b * 512 + i0) * 80);
        const float4* __restrict__ t4 = (const float4*)(targ + ((size_t)b * 512 + j0) * 80);
        #pragma unroll
        for (int q = 0; q < 5; ++q) {
            int idx = q * 256 + t;       // 0..1279
            int r = idx / 20, dq = idx % 20;
            float4 v = p4[r * 20 + dq];
            sp[r][dq*4+0]=v.x; sp[r][dq*4+1]=v.y; sp[r][dq*4+2]=v.z; sp[r][dq*4+3]=v.w;
            float4 w = t4[r * 20 + dq];
            st[r][dq*4+0]=w.x; st[r][dq*4+1]=w.y; st[r][dq*4+2]=w.z; st[r][dq*4+3]=w.w;
        }
        __syncthreads();

        const int tx = t & 15, ty = t >> 4;
        float acc[4][4];
        #pragma unroll
        for (int r = 0; r < 4; ++r)
            #pragma unroll
            for (int c = 0; c < 4; ++c) acc[r][c] = 0.f;

        #pragma unroll 4
        for (int d = 0; d < 80; ++d) {
            float a0 = sp[4*ty+0][d], a1 = sp[4*ty+1][d], a2 = sp[4*ty+2][d], a3 = sp[4*ty+3][d];
            float b0 = st[4*tx+0][d], b1 = st[4*tx+1][d], b2 = st[4*tx+2][d], b3 = st[4*tx+3][d];
            acc[0][0] += fabsf(a0-b0); acc[0][1] += fabsf(a0-b1); acc[0][2] += fabsf(a0-b2); acc[0][3] += fabsf(a0-b3);
            acc[1][0] += fabsf(a1-b0); acc[1][1] += fabsf(a1-b1); acc[1][2] += fabsf(a1-b2); acc[1][3] += fabsf(a1-b3);
            acc[2][0] += fabsf(a2-b0); acc[2][1] += fabsf(a2-b1); acc[2][2] += fabsf(a2-b2); acc[2][3] += fabsf(a2-b3);
            acc[3][0] += fabsf(a3-b0); acc[3][1] += fabsf(a3-b1); acc[3][2] += fabsf(a3-b2); acc[3][3] += fabsf(a3-b3);
        }

        #pragma unroll
        for (int r = 0; r < 4; ++r) {
            #pragma unroll
            for (int c = 0; c < 4; ++c) {
                int i = i0 + 4*ty + r;
                int j = j0 + 4*tx + c;
                float v = acc[r][c];
                v = ((i | j) == 0) ? (v - BIGF) : (v + 2.0f);   // W-transform fold
                Ddiag[((size_t)b * 1023 + (i + j)) * 512 + i] = v;
            }
        }
    } else {
        // fill invalid slots with BIG
        unsigned fid  = bid - 256;                 // 0..1022
        unsigned base = fid * 2048u + (unsigned)t * 8u;
        #pragma unroll
        for (int e = 0; e < 8; ++e) {
            unsigned slot = base + e;              // < 2,095,104
            unsigned rem  = slot % 523776u;        // 1023*512
            int k = (int)(rem >> 9);
            int i = (int)(rem & 511u);
            int j = k - i;
            if ((unsigned)j >= 512u) Ddiag[slot] = BIGF;
        }
    }
}

// ---------------------------------------------------------------------------
// dp_kernel: soft-DTW wavefront DP (min3 approx + W-transform: no warp-add).
// ONE wave per batch, lane owns rows 8*lane..8*lane+7. Cross-lane via
// v_mov_b32_dpp wave_shr:1 (lane 0 keeps BIGF 'old' -> boundary free).
// Per step: 2 DPP + 8 x (v_min3_f32 + v_add) = 18 VALU. 16-deep prefetch,
// launch_bounds(64,1) so the 128 prefetch VGPRs stay live.
// ---------------------------------------------------------------------------
#define STEP(V1, V2, da, db)                                                  \
  {                                                                           \
    float nb1 = __int_as_float(__builtin_amdgcn_update_dpp(                   \
        __float_as_int(BIGF), __float_as_int(V1[7]), 0x138, 0xF, 0xF, false));\
    float nb2 = __int_as_float(__builtin_amdgcn_update_dpp(                   \
        __float_as_int(BIGF), __float_as_int(V2[7]), 0x138, 0xF, 0xF, false));\
    V2[7] = db.w + min3f(V2[6], V1[6], V1[7]);                                \
    V2[6] = db.z + min3f(V2[5], V1[5], V1[6]);                                \
    V2[5] = db.y + min3f(V2[4], V1[4], V1[5]);                                \
    V2[4] = db.x + min3f(V2[3], V1[3], V1[4]);                                \
    V2[3] = da.w + min3f(V2[2], V1[2], V1[3]);                                \
    V2[2] = da.z + min3f(V2[1], V1[1], V1[2]);                                \
    V2[1] = da.y + min3f(V2[0], V1[0], V1[1]);                                \
    V2[0] = da.x + min3f(nb2,   nb1,   V1[0]);                                \
  }

__global__ __launch_bounds__(64, 1) void dp_kernel(
        const float* __restrict__ Ddiag, float* __restrict__ sdtw) {
    const int b    = blockIdx.x;
    const int lane = threadIdx.x;
    const char* __restrict__ base = (const char*)Ddiag + (size_t)b * (1023ull * 512 * 4);
    const unsigned loff = (unsigned)lane * 32u;

    float A[8], B[8];
    #pragma unroll
    for (int r = 0; r < 8; ++r) { A[r] = BIGF; B[r] = BIGF; }

    float4 Pa[16], Pb[16];
    #pragma unroll
    for (int p = 0; p < 16; ++p) {
        const char* s = base + (size_t)p * 2048 + loff;
        Pa[p] = *(const float4*)(s);
        Pb[p] = *(const float4*)(s + 16);
    }

    int k0 = 0;
    for (int t = 0; t < 63; ++t, k0 += 16) {
#define PH(p, Vx, Vy)                                                         \
        STEP(Vx, Vy, Pa[p], Pb[p])                                            \
        {                                                                     \
            int kp = k0 + 16 + (p); kp = (kp > 1022) ? 1022 : kp;             \
            const char* s = base + (size_t)kp * 2048 + loff;                  \
            Pa[p] = *(const float4*)(s);                                      \
            Pb[p] = *(const float4*)(s + 16);                                 \
        }
        PH(0,A,B)  PH(1,B,A)  PH(2,A,B)  PH(3,B,A)
        PH(4,A,B)  PH(5,B,A)  PH(6,A,B)  PH(7,B,A)
        PH(8,A,B)  PH(9,B,A)  PH(10,A,B) PH(11,B,A)
        PH(12,A,B) PH(13,B,A) PH(14,A,B) PH(15,B,A)
#undef PH
    }
    // tail: k = 1008..1022 (15 steps), phases 0..14 already prefetched
    STEP(A,B,Pa[0],Pb[0])   STEP(B,A,Pa[1],Pb[1])   STEP(A,B,Pa[2],Pb[2])
    STEP(B,A,Pa[3],Pb[3])   STEP(A,B,Pa[4],Pb[4])   STEP(B,A,Pa[5],Pb[5])
    STEP(A,B,Pa[6],Pb[6])   STEP(B,A,Pa[7],Pb[7])   STEP(A,B,Pa[8],Pb[8])
    STEP(B,A,Pa[9],Pb[9])   STEP(A,B,Pa[10],Pb[10]) STEP(B,A,Pa[11],Pb[11])
    STEP(A,B,Pa[12],Pb[12]) STEP(B,A,Pa[13],Pb[13]) STEP(A,B,Pa[14],Pb[14])

    if (lane == 63) sdtw[b] = B[7] - 1022.0f;   // undo W-transform at (511,511)
}

// ---------------------------------------------------------------------------
// finalize: duration loss + final scalar.
// ---------------------------------------------------------------------------
__global__ __launch_bounds__(512) void finalize_kernel(
        const float* __restrict__ ldp, const int* __restrict__ dt,
        const float* __restrict__ sdtw, float* __restrict__ out) {
    const int t = threadIdx.x;
    float v = fabsf(ldp[t] - logf((float)dt[t] + 1.0f));
    #pragma unroll
    for (int o = 32; o > 0; o >>= 1) v += __shfl_down(v, o);
    __shared__ float part[8];
    if ((t & 63) == 0) part[t >> 6] = v;
    __syncthreads();
    if (t == 0) {
        float dur = 0.f;
        #pragma unroll
        for (int w = 0; w < 8; ++w) dur += part[w];
        dur *= (1.0f / 512.0f);
        float mel = (sdtw[0] + sdtw[1] + sdtw[2] + sdtw[3]) * (1.0f / (4.0f * 512.0f));
        out[0] = mel + dur;
    }
}

extern "C" void kernel_launch(void* const* d_in, const int* in_sizes, int n_in,
                              void* d_out, int out_size, void* d_ws, size_t ws_size,
                              hipStream_t stream) {
    const float* pred = (const float*)d_in[0];   // mel_pred  [4,512,80]
    const float* targ = (const float*)d_in[1];   // mel_target[4,512,80]
    const float* ldp  = (const float*)d_in[2];   // log_d_pred[4,128]
    const int*   dt   = (const int*)d_in[3];     // d_target  [4,128]
    float* out = (float*)d_out;

    float* Ddiag = (float*)d_ws;                          // 4*1023*512 floats = 8.38 MB
    float* sdtw  = Ddiag + (size_t)4 * 1023 * 512;        // 4 floats

    prep_kernel<<<256 + 1023, 256, 0, stream>>>(pred, targ, Ddiag);
    dp_kernel<<<4, 64, 0, stream>>>(Ddiag, sdtw);
    finalize_kernel<<<1, 512, 0, stream>>>(ldp, dt, sdtw, out);
}

// Round 5
// 77.950 us; speedup vs baseline: 3.7211x; 1.0264x over previous
//
#include <hip/hip_runtime.h>
#include <hip/hip_bf16.h>
#include <hip/hip_fp16.h>
#include <math.h>

#define BIGF 1e8f
#define BIGS 28672.0f   // invalid-cell sentinel in fp16 cost matrix

__device__ inline float min3f(float a, float b, float c) {
    float d;
    asm("v_min3_f32 %0, %1, %2, %3" : "=v"(d) : "v"(a), "v"(b), "v"(c));
    return d;
}

// ---------------------------------------------------------------------------
// prep_kernel: blocks 0..255 compute the cost matrix (fp16, diagonal-major);
// blocks 256..1278 fill INVALID slots of diagonal (bid-256) with BIGS
// (contiguous -> coalesced). W-transform fold: valid cells store D+2; cell
// (0,0) stores plain D00 (start handled by peeled step 0 in the DP kernel).
// ---------------------------------------------------------------------------
__global__ __launch_bounds__(256) void prep_kernel(
        const float* __restrict__ pred, const float* __restrict__ targ,
        __half* __restrict__ Dh) {
    const int bid = blockIdx.x;
    const int t   = threadIdx.x;

    if (bid < 256) {
        const int b  = bid >> 6;
        const int i0 = ((bid >> 3) & 7) * 64;
        const int j0 = (bid & 7) * 64;
        __shared__ float sp[64][81];
        __shared__ float st[64][81];

        const float4* __restrict__ p4 = (const float4*)(pred + ((size_t)b * 512 + i0) * 80);
        const float4* __restrict__ t4 = (const float4*)(targ + ((size_t)b * 512 + j0) * 80);
        #pragma unroll
        for (int q = 0; q < 5; ++q) {
            int idx = q * 256 + t;       // 0..1279
            int r = idx / 20, dq = idx % 20;
            float4 v = p4[r * 20 + dq];
            sp[r][dq*4+0]=v.x; sp[r][dq*4+1]=v.y; sp[r][dq*4+2]=v.z; sp[r][dq*4+3]=v.w;
            float4 w = t4[r * 20 + dq];
            st[r][dq*4+0]=w.x; st[r][dq*4+1]=w.y; st[r][dq*4+2]=w.z; st[r][dq*4+3]=w.w;
        }
        __syncthreads();

        const int tx = t & 15, ty = t >> 4;
        float acc[4][4];
        #pragma unroll
        for (int r = 0; r < 4; ++r)
            #pragma unroll
            for (int c = 0; c < 4; ++c) acc[r][c] = 0.f;

        #pragma unroll 4
        for (int d = 0; d < 80; ++d) {
            float a0 = sp[4*ty+0][d], a1 = sp[4*ty+1][d], a2 = sp[4*ty+2][d], a3 = sp[4*ty+3][d];
            float b0 = st[4*tx+0][d], b1 = st[4*tx+1][d], b2 = st[4*tx+2][d], b3 = st[4*tx+3][d];
            acc[0][0] += fabsf(a0-b0); acc[0][1] += fabsf(a0-b1); acc[0][2] += fabsf(a0-b2); acc[0][3] += fabsf(a0-b3);
            acc[1][0] += fabsf(a1-b0); acc[1][1] += fabsf(a1-b1); acc[1][2] += fabsf(a1-b2); acc[1][3] += fabsf(a1-b3);
            acc[2][0] += fabsf(a2-b0); acc[2][1] += fabsf(a2-b1); acc[2][2] += fabsf(a2-b2); acc[2][3] += fabsf(a2-b3);
            acc[3][0] += fabsf(a3-b0); acc[3][1] += fabsf(a3-b1); acc[3][2] += fabsf(a3-b2); acc[3][3] += fabsf(a3-b3);
        }

        #pragma unroll
        for (int r = 0; r < 4; ++r) {
            #pragma unroll
            for (int c = 0; c < 4; ++c) {
                int i = i0 + 4*ty + r;
                int j = j0 + 4*tx + c;
                float v = acc[r][c];
                float w = ((i | j) == 0) ? v : (v + 2.0f);   // W-transform fold
                Dh[((size_t)b * 1023 + (i + j)) * 512 + i] = __float2half(w);
            }
        }
    } else {
        // fill invalid slots of diagonal k for all 4 batches (contiguous ranges)
        const int k  = bid - 256;               // 0..1022
        const int lo = (k > 511) ? (k - 511) : 0;
        const int hi = (k < 511) ? k : 511;
        const __half big = __float2half(BIGS);
        #pragma unroll
        for (int b = 0; b < 4; ++b) {
            __half* row = Dh + ((size_t)b * 1023 + k) * 512;
            int i1 = t;
            int i2 = t + 256;
            if (i1 < lo || i1 > hi) row[i1] = big;
            if (i2 < lo || i2 > hi) row[i2] = big;
        }
    }
}

// ---------------------------------------------------------------------------
// dp_kernel: soft-DTW wavefront DP (min3 approx + W-transform, fp16 costs).
// Wave 0 of each block: DP for batch b (lane owns rows 8*lane..8*lane+7,
// cross-lane via DPP wave_shr:1, 16-deep uint4 prefetch = 1 load/step).
// Wave 1 of block 0: duration loss. Both accumulate into out[0] atomically
// (out zeroed by hipMemsetAsync each call).
// ---------------------------------------------------------------------------
#define DPPSHR(x) __int_as_float(__builtin_amdgcn_update_dpp(                 \
        __float_as_int(BIGF), __float_as_int(x), 0x138, 0xF, 0xF, false))

#define STEP(V1, V2, P)                                                       \
  {                                                                           \
    const __half2* hp_ = (const __half2*)&(P);                                \
    float2 f0_ = __half22float2(hp_[0]);                                      \
    float2 f1_ = __half22float2(hp_[1]);                                      \
    float2 f2_ = __half22float2(hp_[2]);                                      \
    float2 f3_ = __half22float2(hp_[3]);                                      \
    float nb1 = DPPSHR(V1[7]);                                                \
    float nb2 = DPPSHR(V2[7]);                                                \
    V2[7] = f3_.y + min3f(V2[6], V1[6], V1[7]);                               \
    V2[6] = f3_.x + min3f(V2[5], V1[5], V1[6]);                               \
    V2[5] = f2_.y + min3f(V2[4], V1[4], V1[5]);                               \
    V2[4] = f2_.x + min3f(V2[3], V1[3], V1[4]);                               \
    V2[3] = f1_.y + min3f(V2[2], V1[2], V1[3]);                               \
    V2[2] = f1_.x + min3f(V2[1], V1[1], V1[2]);                               \
    V2[1] = f0_.y + min3f(V2[0], V1[0], V1[1]);                               \
    V2[0] = f0_.x + min3f(nb2,   nb1,   V1[0]);                               \
  }

__global__ __launch_bounds__(128, 1) void dp_kernel(
        const __half* __restrict__ Dh,
        const float* __restrict__ ldp, const int* __restrict__ dt,
        float* __restrict__ out) {
    const int tid = threadIdx.x;
    if (tid >= 64) {
        if (blockIdx.x == 0) {
            // duration loss wave
            const int l = tid - 64;
            float s = 0.f;
            #pragma unroll
            for (int q = 0; q < 8; ++q) {
                int idx = l * 8 + q;
                s += fabsf(ldp[idx] - logf((float)dt[idx] + 1.0f));
            }
            #pragma unroll
            for (int o = 32; o > 0; o >>= 1) s += __shfl_down(s, o);
            if (l == 0) atomicAdd(out, s * (1.0f / 512.0f));
        }
        return;
    }

    const int b    = blockIdx.x;
    const int lane = tid;
    const char* __restrict__ base = (const char*)(Dh + (size_t)b * 1023 * 512);
    const unsigned loff = (unsigned)lane * 16u;

    float A[8], B[8];
    #pragma unroll
    for (int r = 0; r < 8; ++r) { A[r] = BIGF; B[r] = BIGF; }

    // peeled step k=0: only cell (0,0) is valid; W_0[0] = D00
    {
        uint4 q0 = *(const uint4*)(base + loff);
        float c00 = __half2float(*(const __half*)&q0.x);
        B[0] = (lane == 0) ? c00 : BIGF;
    }

    // prefetch diagonals 1..16
    uint4 P[16];
    #pragma unroll
    for (int p = 0; p < 16; ++p)
        P[p] = *(const uint4*)(base + (size_t)(1 + p) * 1024 + loff);

    // main loop: steps k = 1..1008 (63 x 16), parity: odd k = STEP(B,A)
    int k0 = 1;
    for (int t = 0; t < 63; ++t, k0 += 16) {
#define PH(p, Vx, Vy)                                                         \
        STEP(Vx, Vy, P[p])                                                    \
        P[p] = *(const uint4*)(base + (size_t)(k0 + 16 + p) * 1024 + loff);
        PH(0,B,A)  PH(1,A,B)  PH(2,B,A)  PH(3,A,B)
        PH(4,B,A)  PH(5,A,B)  PH(6,B,A)  PH(7,A,B)
        PH(8,B,A)  PH(9,A,B)  PH(10,B,A) PH(11,A,B)
        PH(12,B,A) PH(13,A,B) PH(14,B,A) PH(15,A,B)
#undef PH
    }
    // tail: k = 1009..1022 (14 steps), P[0..13] hold diagonals 1009..1022
    STEP(B,A,P[0])  STEP(A,B,P[1])  STEP(B,A,P[2])  STEP(A,B,P[3])
    STEP(B,A,P[4])  STEP(A,B,P[5])  STEP(B,A,P[6])  STEP(A,B,P[7])
    STEP(B,A,P[8])  STEP(A,B,P[9])  STEP(B,A,P[10]) STEP(A,B,P[11])
    STEP(B,A,P[12]) STEP(A,B,P[13])

    // k=1022 (even) wrote B; cell (511,511) = lane 63, r=7. Undo W-transform.
    if (lane == 63) atomicAdd(out, (B[7] - 1022.0f) * (1.0f / 2048.0f));
}

extern "C" void kernel_launch(void* const* d_in, const int* in_sizes, int n_in,
                              void* d_out, int out_size, void* d_ws, size_t ws_size,
                              hipStream_t stream) {
    const float* pred = (const float*)d_in[0];   // mel_pred  [4,512,80]
    const float* targ = (const float*)d_in[1];   // mel_target[4,512,80]
    const float* ldp  = (const float*)d_in[2];   // log_d_pred[4,128]
    const int*   dt   = (const int*)d_in[3];     // d_target  [4,128]
    float* out = (float*)d_out;

    __half* Dh = (__half*)d_ws;                  // 4*1023*512 halves = 4.19 MB

    hipMemsetAsync(out, 0, sizeof(float), stream);
    prep_kernel<<<256 + 1023, 256, 0, stream>>>(pred, targ, Dh);
    dp_kernel<<<4, 128, 0, stream>>>(Dh, ldp, dt, out);
}

// Round 6
// 73.118 us; speedup vs baseline: 3.9670x; 1.0661x over previous
//
#include <hip/hip_runtime.h>
#include <hip/hip_bf16.h>
#include <hip/hip_fp16.h>
#include <math.h>

#define BIGF 1e8f
#define BIGS 28672.0f   // invalid-cell sentinel in fp16 cost matrix

__device__ inline float min3f(float a, float b, float c) {
    float d;
    asm("v_min3_f32 %0, %1, %2, %3" : "=v"(d) : "v"(a), "v"(b), "v"(c));
    return d;
}
// D = f32(lo/hi half of pw) * 1.0f + c   (fused fp16 convert + add)
__device__ inline float addh_lo(unsigned pw, float c) {
    float d;
    asm("v_fma_mix_f32 %0, %1, 1.0, %2 op_sel:[0,0,0] op_sel_hi:[1,0,0]"
        : "=v"(d) : "v"(pw), "v"(c));
    return d;
}
__device__ inline float addh_hi(unsigned pw, float c) {
    float d;
    asm("v_fma_mix_f32 %0, %1, 1.0, %2 op_sel:[1,0,0] op_sel_hi:[1,0,0]"
        : "=v"(d) : "v"(pw), "v"(c));
    return d;
}

// ---------------------------------------------------------------------------
// prep_kernel: unchanged from round 5 (proven, absmax 0.0).
// blocks 0..255: fp16 cost matrix, diagonal-major, W-transform fold (D+2,
// cell (0,0) stores plain D00). blocks 256..1278: fill invalid slots of one
// diagonal with BIGS.
// ---------------------------------------------------------------------------
__global__ __launch_bounds__(256) void prep_kernel(
        const float* __restrict__ pred, const float* __restrict__ targ,
        __half* __restrict__ Dh) {
    const int bid = blockIdx.x;
    const int t   = threadIdx.x;

    if (bid < 256) {
        const int b  = bid >> 6;
        const int i0 = ((bid >> 3) & 7) * 64;
        const int j0 = (bid & 7) * 64;
        __shared__ float sp[64][81];
        __shared__ float st[64][81];

        const float4* __restrict__ p4 = (const float4*)(pred + ((size_t)b * 512 + i0) * 80);
        const float4* __restrict__ t4 = (const float4*)(targ + ((size_t)b * 512 + j0) * 80);
        #pragma unroll
        for (int q = 0; q < 5; ++q) {
            int idx = q * 256 + t;       // 0..1279
            int r = idx / 20, dq = idx % 20;
            float4 v = p4[r * 20 + dq];
            sp[r][dq*4+0]=v.x; sp[r][dq*4+1]=v.y; sp[r][dq*4+2]=v.z; sp[r][dq*4+3]=v.w;
            float4 w = t4[r * 20 + dq];
            st[r][dq*4+0]=w.x; st[r][dq*4+1]=w.y; st[r][dq*4+2]=w.z; st[r][dq*4+3]=w.w;
        }
        __syncthreads();

        const int tx = t & 15, ty = t >> 4;
        float acc[4][4];
        #pragma unroll
        for (int r = 0; r < 4; ++r)
            #pragma unroll
            for (int c = 0; c < 4; ++c) acc[r][c] = 0.f;

        #pragma unroll 4
        for (int d = 0; d < 80; ++d) {
            float a0 = sp[4*ty+0][d], a1 = sp[4*ty+1][d], a2 = sp[4*ty+2][d], a3 = sp[4*ty+3][d];
            float b0 = st[4*tx+0][d], b1 = st[4*tx+1][d], b2 = st[4*tx+2][d], b3 = st[4*tx+3][d];
            acc[0][0] += fabsf(a0-b0); acc[0][1] += fabsf(a0-b1); acc[0][2] += fabsf(a0-b2); acc[0][3] += fabsf(a0-b3);
            acc[1][0] += fabsf(a1-b0); acc[1][1] += fabsf(a1-b1); acc[1][2] += fabsf(a1-b2); acc[1][3] += fabsf(a1-b3);
            acc[2][0] += fabsf(a2-b0); acc[2][1] += fabsf(a2-b1); acc[2][2] += fabsf(a2-b2); acc[2][3] += fabsf(a2-b3);
            acc[3][0] += fabsf(a3-b0); acc[3][1] += fabsf(a3-b1); acc[3][2] += fabsf(a3-b2); acc[3][3] += fabsf(a3-b3);
        }

        #pragma unroll
        for (int r = 0; r < 4; ++r) {
            #pragma unroll
            for (int c = 0; c < 4; ++c) {
                int i = i0 + 4*ty + r;
                int j = j0 + 4*tx + c;
                float v = acc[r][c];
                float w = ((i | j) == 0) ? v : (v + 2.0f);   // W-transform fold
                Dh[((size_t)b * 1023 + (i + j)) * 512 + i] = __float2half(w);
            }
        }
    } else {
        const int k  = bid - 256;               // 0..1022
        const int lo = (k > 511) ? (k - 511) : 0;
        const int hi = (k < 511) ? k : 511;
        const __half big = __float2half(BIGS);
        #pragma unroll
        for (int b = 0; b < 4; ++b) {
            __half* row = Dh + ((size_t)b * 1023 + k) * 512;
            int i1 = t;
            int i2 = t + 256;
            if (i1 < lo || i1 > hi) row[i1] = big;
            if (i2 < lo || i2 > hi) row[i2] = big;
        }
    }
}

// ---------------------------------------------------------------------------
// dp_kernel: soft-DTW wavefront DP (min3 + W-transform, fp16 costs).
// Manual software pipeline: 32 asm-volatile global_load_dwordx4 in flight
// per wave (compiler cannot shrink the window), counted s_waitcnt vmcnt(31)
// per step + sched_barrier(0) (rule #18). Per step: 2 DPP + 8 v_min3_f32 +
// 8 v_fma_mix_f32 (fused f16 cvt+add) + 1 voff add.
// ---------------------------------------------------------------------------
#define DPPSHR(x) __int_as_float(__builtin_amdgcn_update_dpp(                 \
        __float_as_int(BIGF), __float_as_int(x), 0x138, 0xF, 0xF, false))

#define STEP(V1, V2, Q)                                                       \
  {                                                                           \
    float nb1 = DPPSHR(V1[7]);                                                \
    float nb2 = DPPSHR(V2[7]);                                                \
    V2[7] = addh_hi(Q.w, min3f(V2[6], V1[6], V1[7]));                         \
    V2[6] = addh_lo(Q.w, min3f(V2[5], V1[5], V1[6]));                         \
    V2[5] = addh_hi(Q.z, min3f(V2[4], V1[4], V1[5]));                         \
    V2[4] = addh_lo(Q.z, min3f(V2[3], V1[3], V1[4]));                         \
    V2[3] = addh_hi(Q.y, min3f(V2[2], V1[2], V1[3]));                         \
    V2[2] = addh_lo(Q.y, min3f(V2[1], V1[1], V1[2]));                         \
    V2[1] = addh_hi(Q.x, min3f(V2[0], V1[0], V1[1]));                         \
    V2[0] = addh_lo(Q.x, min3f(nb2,   nb1,   V1[0]));                         \
  }

__global__ __launch_bounds__(128, 1) void dp_kernel(
        const __half* __restrict__ Dh,
        const float* __restrict__ ldp, const int* __restrict__ dt,
        float* __restrict__ out) {
    const int tid = threadIdx.x;
    if (tid >= 64) {
        if (blockIdx.x == 0) {
            const int l = tid - 64;
            float s = 0.f;
            #pragma unroll
            for (int q = 0; q < 8; ++q) {
                int idx = l * 8 + q;
                s += fabsf(ldp[idx] - logf((float)dt[idx] + 1.0f));
            }
            #pragma unroll
            for (int o = 32; o > 0; o >>= 1) s += __shfl_down(s, o);
            if (l == 0) atomicAdd(out, s * (1.0f / 512.0f));
        }
        return;
    }

    const int b    = blockIdx.x;
    const int lane = tid;
    const char* __restrict__ base = (const char*)(Dh + (size_t)b * 1023 * 512);

    float A[8], B[8];
    #pragma unroll
    for (int r = 0; r < 8; ++r) { A[r] = BIGF; B[r] = BIGF; }

    // peeled step k=0: only cell (0,0) valid; W_0[0] = D00 (stored w/o +2)
    {
        float c00 = __half2float(*(const __half*)base);
        B[0] = (lane == 0) ? c00 : BIGF;
    }
    __builtin_amdgcn_sched_barrier(0);

    // issue 32 loads: diagonals 1..32 (1 KB per diagonal, lane offset 16B)
    unsigned voff = (unsigned)lane * 16u + 1024u;
    uint4 P[32];
    #pragma unroll
    for (int p = 0; p < 32; ++p) {
        asm volatile("global_load_dwordx4 %0, %1, %2"
                     : "=v"(P[p]) : "v"(voff), "s"(base) : "memory");
        voff += 1024u;
    }

    // main loop: steps k = 1..992 (31 groups x 32). k0 = 1+32t (odd), so
    // even phase p -> odd k -> STEP(B,A); odd p -> STEP(A,B).
    for (int t = 0; t < 31; ++t) {
#define PH(p, Vx, Vy)                                                         \
        asm volatile("s_waitcnt vmcnt(31)" ::: "memory");                     \
        __builtin_amdgcn_sched_barrier(0);                                    \
        STEP(Vx, Vy, P[p])                                                    \
        asm volatile("global_load_dwordx4 %0, %1, %2"                         \
                     : "=v"(P[p]) : "v"(voff), "s"(base) : "memory");         \
        voff += 1024u;
        PH(0,B,A)   PH(1,A,B)   PH(2,B,A)   PH(3,A,B)
        PH(4,B,A)   PH(5,A,B)   PH(6,B,A)   PH(7,A,B)
        PH(8,B,A)   PH(9,A,B)   PH(10,B,A)  PH(11,A,B)
        PH(12,B,A)  PH(13,A,B)  PH(14,B,A)  PH(15,A,B)
        PH(16,B,A)  PH(17,A,B)  PH(18,B,A)  PH(19,A,B)
        PH(20,B,A)  PH(21,A,B)  PH(22,B,A)  PH(23,A,B)
        PH(24,B,A)  PH(25,A,B)  PH(26,B,A)  PH(27,A,B)
        PH(28,B,A)  PH(29,A,B)  PH(30,B,A)  PH(31,A,B)
#undef PH
    }

    // tail: k = 993..1022 (30 steps) in P[0..29] (issued by group t=30)
    asm volatile("s_waitcnt vmcnt(0)" ::: "memory");
    __builtin_amdgcn_sched_barrier(0);
    STEP(B,A,P[0])   STEP(A,B,P[1])   STEP(B,A,P[2])   STEP(A,B,P[3])
    STEP(B,A,P[4])   STEP(A,B,P[5])   STEP(B,A,P[6])   STEP(A,B,P[7])
    STEP(B,A,P[8])   STEP(A,B,P[9])   STEP(B,A,P[10])  STEP(A,B,P[11])
    STEP(B,A,P[12])  STEP(A,B,P[13])  STEP(B,A,P[14])  STEP(A,B,P[15])
    STEP(B,A,P[16])  STEP(A,B,P[17])  STEP(B,A,P[18])  STEP(A,B,P[19])
    STEP(B,A,P[20])  STEP(A,B,P[21])  STEP(B,A,P[22])  STEP(A,B,P[23])
    STEP(B,A,P[24])  STEP(A,B,P[25])  STEP(B,A,P[26])  STEP(A,B,P[27])
    STEP(B,A,P[28])  STEP(A,B,P[29])

    // k=1022 (even) wrote B; cell (511,511) = lane 63, r=7. Undo W-transform.
    if (lane == 63) atomicAdd(out, (B[7] - 1022.0f) * (1.0f / 2048.0f));
}

extern "C" void kernel_launch(void* const* d_in, const int* in_sizes, int n_in,
                              void* d_out, int out_size, void* d_ws, size_t ws_size,
                              hipStream_t stream) {
    const float* pred = (const float*)d_in[0];   // mel_pred  [4,512,80]
    const float* targ = (const float*)d_in[1];   // mel_target[4,512,80]
    const float* ldp  = (const float*)d_in[2];   // log_d_pred[4,128]
    const int*   dt   = (const int*)d_in[3];     // d_target  [4,128]
    float* out = (float*)d_out;

    __half* Dh = (__half*)d_ws;                  // 4*1023*512 halves = 4.19 MB

    hipMemsetAsync(out, 0, sizeof(float), stream);
    prep_kernel<<<256 + 1023, 256, 0, stream>>>(pred, targ, Dh);
    dp_kernel<<<4, 128, 0, stream>>>(Dh, ldp, dt, out);
}